// Round 1
// baseline (8774.377 us; speedup 1.0000x reference)
//
#include <hip/hip_runtime.h>

// ---------------------------------------------------------------------------
// 4-layer tanh RNN, T=256, B=128, H=1024 (fp32 in/out), MI355X gfx950.
//
// Round 3 changes vs round 2 (8426 us):
//  * Ring reads: per-load sc0/sc1 coherent loads (2-deep vmcnt pipeline that
//    exposed ~900cy latency on every one of 16 K-steps) replaced by ONE
//    agent-scope acquire fence (buffer_inv) per step after the flag poll,
//    then plain cached bf16x8 loads. Compiler pipelines them deeply; ring
//    lines become L2/L3 hits (same-layer blocks on an XCD share h lines).
//    Producers keep writing through to the coherence point (relaxed agent
//    atomics), so readers only need invalidate -- no wbl2, no HBM churn.
//  * MFMA operands swapped: acc = mfma(wfrag, afrag). D-fragment then holds
//    4 consecutive n-columns per lane -> publish is one packed 8B atomic
//    store per thread per m-half (was 8 scattered 2B atomics), 64B-aligned.
//  * Flags: one monotonic counter per layer (atomicAdd 1/block/step);
//    consumers poll 3 dwords (own>=32t, prev>=32(t+1), back>=32(t-7))
//    instead of 32-lane flag gathers.
// ---------------------------------------------------------------------------

#define TT 256
#define BB 128
#define HH 1024
#define LL 4
#define RING 8
#define MAT (BB * HH)          // 131072 elements per [B,H] matrix

typedef __attribute__((ext_vector_type(4))) float  float4v;
typedef __attribute__((ext_vector_type(8))) __bf16 bf16x8;
typedef __attribute__((ext_vector_type(8))) unsigned short ushort8;

__device__ inline unsigned short bf16r(float f) {
    union { float f; unsigned u; } v; v.f = f;
    unsigned u = v.u;
    u += 0x7fffu + ((u >> 16) & 1u);     // round-to-nearest-even
    return (unsigned short)(u >> 16);
}

__device__ inline bf16x8 pack8(float4v a, float4v b) {
    ushort8 r;
    r[0] = bf16r(a[0]); r[1] = bf16r(a[1]); r[2] = bf16r(a[2]); r[3] = bf16r(a[3]);
    r[4] = bf16r(b[0]); r[5] = bf16r(b[1]); r[6] = bf16r(b[2]); r[7] = bf16r(b[3]);
    return __builtin_bit_cast(bf16x8, r);
}

__device__ inline float4v mfma16(bf16x8 a, bf16x8 b, float4v c) {
    return __builtin_amdgcn_mfma_f32_16x16x32_bf16(a, b, c, 0, 0, 0);
}

__device__ inline float fast_tanh(float x) {
    float ax = fabsf(x);
    float e  = __expf(-2.0f * ax);
    float r  = (1.0f - e) / (1.0f + e);
    return copysignf(r, x);
}

// --------------------------- prep: flags + h init ---------------------------
__global__ void rnn_prep(const float* __restrict__ hxs,
                         unsigned* __restrict__ F,
                         unsigned short* __restrict__ ring) {
    int i = blockIdx.x * blockDim.x + threadIdx.x;
    if (i < 256) F[i] = 0u;              // counters live at F[g*64], g=0..3
    int stride = gridDim.x * blockDim.x;
    for (int idx = i; idx < LL * MAT; idx += stride) {
        int g = idx >> 17;               // / MAT
        int rem = idx & (MAT - 1);
        // initial h for layer g -> ring slot RING-1 (read at t=0 as (t-1)%RING)
        ring[(size_t)(g * RING + RING - 1) * MAT + rem] = bf16r(hxs[idx]);
    }
    // end-of-kernel implicit release flushes these to the coherence point
}

// --------------------------- main pipelined kernel --------------------------
__global__ __launch_bounds__(512, 2) void rnn_pipeline(
    const float* __restrict__ xin,   // [T][B][H] fp32
    const float* __restrict__ Wih,   // [L][H][H]
    const float* __restrict__ bih,   // [L][H]
    const float* __restrict__ Whh,   // [L][H][H]
    const float* __restrict__ bhh,   // [L][H]
    float* __restrict__ out,         // [T*B*H + L*B*H]
    unsigned* __restrict__ F,        // counters: F[g*64] = 32*(steps done)
    unsigned short* __restrict__ ring) // [L][RING][B*H] bf16
{
    const int tid  = threadIdx.x;
    const int lane = tid & 63;
    const int wid  = tid >> 6;       // 0..7
    const int ks   = wid & 3;        // K-slice: 0,1 = x-half; 2,3 = h-half
    const int mh   = wid >> 2;       // m-half (64 rows)
    const int g    = blockIdx.x >> 5;  // layer
    const int nt   = blockIdx.x & 31;  // n-tile
    const int n0   = nt * 32;

    __shared__ float4v lds_part[8 * 4 * 2 * 64];   // [wid][mt][nt2][lane] = 64KB

    const int rA = lane & 15;        // fragment row/col within tile
    const int qA = lane >> 4;        // quad -> k offset *8

    // ---- load weight fragments into registers (once) ----
    // wfrag[nt2][ki]: lane&15 = n-row (within 16), 8 k-elements. Used as the
    // MFMA A-operand (so D rows = n, D cols = m -> n contiguous in regs).
    bf16x8 wfrag[2][16];
    {
        const float* Wsrc = (ks < 2) ? (Wih + (size_t)g * HH * HH)
                                     : (Whh + (size_t)g * HH * HH);
        const int kofs = (ks & 1) * 512;
        #pragma unroll
        for (int nt2 = 0; nt2 < 2; ++nt2) {
            const int n = n0 + nt2 * 16 + rA;
            const float* rowp = Wsrc + (size_t)n * HH + kofs + qA * 8;
            #pragma unroll
            for (int ki = 0; ki < 16; ++ki) {
                float4v f0 = *(const float4v*)(rowp + ki * 32);
                float4v f1 = *(const float4v*)(rowp + ki * 32 + 4);
                wfrag[nt2][ki] = pack8(f0, f1);
            }
        }
    }

    // ---- reduce-phase constants ----
    // Thread owns (m-row, 4 consecutive n) per m-half. Lane mapping chosen so
    // 4 consecutive lanes cover 32 contiguous bytes of a ring row.
    const int rest0 = tid >> 6;
    const int nt2r  = rest0 & 1;
    const int mtr   = (rest0 >> 1) & 3;
    const int l2    = lane;
    const int n4    = l2 & 3;            // which n-quad within 16
    const int mi    = l2 >> 2;           // m within 16
    const int lidx  = n4 * 16 + mi;      // LDS lane slot holding (mi, n4)
    const int nbase = n0 + nt2r * 16 + n4 * 4;
    float4v biasv;
    {
        float4v bi = *(const float4v*)(bih + (size_t)g * HH + nbase);
        float4v bh = *(const float4v*)(bhh + (size_t)g * HH + nbase);
        biasv = bi + bh;
    }

    // ---- A-operand lane offset (element units within a [B,H] matrix) ----
    const int aoff = (mh * 64 + rA) * HH + (ks & 1) * 512 + qA * 8;
    const bool is_x = (ks < 2);

    const unsigned short* ringL = ring + (size_t)g * RING * MAT;
    const unsigned short* ringP = (g > 0) ? ring + (size_t)(g - 1) * RING * MAT
                                          : (const unsigned short*)0;
    unsigned short* ringM = ring + (size_t)g * RING * MAT;

    for (int t = 0; t < TT; ++t) {
        // -------- wait for dependencies (wave 0 polls 3 counters) --------
        if (wid == 0) {
            int fidx = g; unsigned tgt = 0u; bool act = false;
            if (lane == 0) {                       // own layer h_{t-1} complete
                act = true; tgt = 32u * (unsigned)t;
            } else if (lane == 1 && g > 0) {       // prev layer produced x_t
                act = true; fidx = g - 1; tgt = 32u * (unsigned)(t + 1);
            } else if (lane == 2 && g < 3 && t >= RING) {  // ring backpressure
                act = true; fidx = g + 1; tgt = 32u * (unsigned)(t - RING + 1);
            }
            for (;;) {
                bool ok = true;
                if (act) {
                    unsigned v = __hip_atomic_load(F + fidx * 64,
                                     __ATOMIC_RELAXED, __HIP_MEMORY_SCOPE_AGENT);
                    ok = (v >= tgt);
                }
                if (__ballot(!ok) == 0ull) break;
                __builtin_amdgcn_s_sleep(2);
            }
            // one invalidate per step: subsequent normal loads (any wave on
            // this CU) see the coherence point. No wbl2 anywhere.
            __builtin_amdgcn_fence(__ATOMIC_ACQUIRE, "agent");
        }
        __syncthreads();

        // -------- fused GEMM over this wave's K-slice --------
        float4v acc[4][2];
        #pragma unroll
        for (int mt = 0; mt < 4; ++mt) {
            acc[mt][0] = (float4v)0.0f;
            acc[mt][1] = (float4v)0.0f;
        }

        if (is_x && g == 0) {
            // layer-0 x half: plain cached fp32 loads from xin + pack
            const float* xsrc = xin + (size_t)t * MAT;
            #pragma unroll
            for (int ki = 0; ki < 16; ++ki) {
                #pragma unroll
                for (int mt = 0; mt < 4; ++mt) {
                    const float* p = xsrc + aoff + mt * (16 * HH) + ki * 32;
                    float4v f0 = *(const float4v*)p;
                    float4v f1 = *(const float4v*)(p + 4);
                    bf16x8 a = pack8(f0, f1);
                    acc[mt][0] = mfma16(wfrag[0][ki], a, acc[mt][0]);
                    acc[mt][1] = mfma16(wfrag[1][ki], a, acc[mt][1]);
                }
            }
        } else {
            // ring-sourced half: cached bf16x8 loads (fresh after the acquire
            // invalidate), compiler-pipelined.
            const unsigned short* asrc =
                is_x ? (ringP + (size_t)(t & (RING - 1)) * MAT)
                     : (ringL + (size_t)((t + RING - 1) & (RING - 1)) * MAT);
            const unsigned short* ap = asrc + aoff;
            #pragma unroll
            for (int ki = 0; ki < 16; ++ki) {
                #pragma unroll
                for (int mt = 0; mt < 4; ++mt) {
                    bf16x8 a = *(const bf16x8*)(ap + mt * (16 * HH) + ki * 32);
                    acc[mt][0] = mfma16(wfrag[0][ki], a, acc[mt][0]);
                    acc[mt][1] = mfma16(wfrag[1][ki], a, acc[mt][1]);
                }
            }
        }

        // -------- partials -> LDS --------
        #pragma unroll
        for (int mt = 0; mt < 4; ++mt)
            #pragma unroll
            for (int nt2 = 0; nt2 < 2; ++nt2)
                lds_part[((wid * 4 + mt) * 2 + nt2) * 64 + lane] = acc[mt][nt2];
        __syncthreads();

        // -------- reduce 4 K-slices + bias + tanh + packed stores --------
        unsigned short* ringW = ringM + (size_t)(t & (RING - 1)) * MAT;
        #pragma unroll
        for (int s = 0; s < 2; ++s) {           // s = m-half
            float4v sum = lds_part[(((s * 4 + 0) * 4 + mtr) * 2 + nt2r) * 64 + lidx];
            #pragma unroll
            for (int k2 = 1; k2 < 4; ++k2)
                sum += lds_part[(((s * 4 + k2) * 4 + mtr) * 2 + nt2r) * 64 + lidx];
            sum += biasv;
            float vals[4];
            #pragma unroll
            for (int r = 0; r < 4; ++r) vals[r] = fast_tanh(sum[r]);

            const int m = s * 64 + mtr * 16 + mi;
            const size_t eo = (size_t)m * HH + nbase;

            // ring publish: one packed 8B relaxed agent store (write-through)
            union { unsigned short us[4]; unsigned long long u; } pk;
            #pragma unroll
            for (int r = 0; r < 4; ++r) pk.us[r] = bf16r(vals[r]);
            __hip_atomic_store((unsigned long long*)(ringW + eo), pk.u,
                               __ATOMIC_RELAXED, __HIP_MEMORY_SCOPE_AGENT);

            if (g == 3) {
                float4v o;
                #pragma unroll
                for (int r = 0; r < 4; ++r) o[r] = vals[r];
                *(float4v*)(out + (size_t)t * MAT + eo) = o;
            }
            if (t == TT - 1) {
                float4v o;
                #pragma unroll
                for (int r = 0; r < 4; ++r) o[r] = vals[r];
                *(float4v*)(out + (size_t)TT * MAT + (size_t)g * MAT + eo) = o;
            }
        }

        // -------- publish progress --------
        // Drain this wave's ring stores to the coherence point, then barrier
        // (all waves drained), then one relaxed counter bump per block.
        asm volatile("s_waitcnt vmcnt(0)" ::: "memory");
        __syncthreads();
        if (tid == 0)
            __hip_atomic_fetch_add(F + g * 64, 1u,
                                   __ATOMIC_RELAXED, __HIP_MEMORY_SCOPE_AGENT);
    }
}

// ------------------------------- launcher -----------------------------------
extern "C" void kernel_launch(void* const* d_in, const int* in_sizes, int n_in,
                              void* d_out, int out_size, void* d_ws, size_t ws_size,
                              hipStream_t stream) {
    const float* xin = (const float*)d_in[0];
    const float* hxs = (const float*)d_in[1];
    const float* Wih = (const float*)d_in[2];
    const float* bih = (const float*)d_in[3];
    const float* Whh = (const float*)d_in[4];
    const float* bhh = (const float*)d_in[5];
    float* out = (float*)d_out;

    unsigned* F = (unsigned*)d_ws;
    unsigned short* ring = (unsigned short*)((char*)d_ws + 1024);
    // ws usage: 1KB flags/counters + 4*8*131072*2B = ~8.4 MB

    rnn_prep<<<256, 256, 0, stream>>>(hxs, F, ring);
    rnn_pipeline<<<128, 512, 0, stream>>>(xin, Wih, bih, Whh, bhh, out, F, ring);
}